// Round 1
// baseline (783.770 us; speedup 1.0000x reference)
//
#include <hip/hip_runtime.h>
#include <hip/hip_bf16.h>
#include <math.h>

#define Hdim 128
#define NCn  8000
#define NVn  16000
#define NE   60000
#define LITERS 10
#define NCB (NCn / 32)   // 250 c-blocks
#define NVB (NVn / 32)   // 500 v-blocks

typedef __attribute__((ext_vector_type(8))) short s8v;   // 8 x bf16 (4 VGPRs)
typedef __attribute__((ext_vector_type(4))) float f4v;   // MFMA acc / float4

__device__ __forceinline__ float elu_f(float x) { return x > 0.0f ? x : (expf(x) - 1.0f); }
__device__ __forceinline__ float sigm_f(float x) { return 1.0f / (1.0f + expf(-x)); }
__device__ __forceinline__ unsigned short f2b(float x) {
    __hip_bfloat16 h = __float2bfloat16(x); return *(unsigned short*)&h;
}
__device__ __forceinline__ float b2f(unsigned short u) {
    __hip_bfloat16 h; *(unsigned short*)&h = u; return __bfloat162float(h);
}

// ---------------- init: h = LN(0.1*f*W_in + b_in), fp32 + bf16 mirror ----------------
__global__ void init_kernel(const float* __restrict__ cf, const float* __restrict__ vf,
                            const float* __restrict__ Wc, const float* __restrict__ bc,
                            const float* __restrict__ Wv, const float* __restrict__ bv,
                            const float* __restrict__ gc, const float* __restrict__ bcl,
                            const float* __restrict__ gv, const float* __restrict__ bvl,
                            float* __restrict__ hc, float* __restrict__ hv,
                            unsigned short* __restrict__ hcb, unsigned short* __restrict__ hvb) {
    int node = blockIdx.x;
    int lane = threadIdx.x;  // 64 threads, 2 elements each
    const float *Win, *bin, *g, *bl;
    float f;
    float* outp;
    unsigned short* outb;
    if (node < NCn) {
        f = cf[node]; Win = Wc; bin = bc; g = gc; bl = bcl;
        outp = hc + (size_t)node * Hdim; outb = hcb + (size_t)node * Hdim;
    } else {
        int n2 = node - NCn;
        f = vf[n2]; Win = Wv; bin = bv; g = gv; bl = bvl;
        outp = hv + (size_t)n2 * Hdim; outb = hvb + (size_t)n2 * Hdim;
    }
    f *= 0.1f;
    float x0 = f * Win[lane] + bin[lane];
    float x1 = f * Win[lane + 64] + bin[lane + 64];
    float s = x0 + x1;
    float sq = x0 * x0 + x1 * x1;
    #pragma unroll
    for (int off = 32; off > 0; off >>= 1) {
        s += __shfl_xor(s, off);
        sq += __shfl_xor(sq, off);
    }
    float m = s * (1.0f / 128.0f);
    float v = sq * (1.0f / 128.0f) - m * m;
    float inv = 1.0f / sqrtf(v + 1e-6f);
    float o0 = g[lane]      * (x0 - m) * inv + bl[lane];
    float o1 = g[lane + 64] * (x1 - m) * inv + bl[lane + 64];
    outp[lane] = o0; outp[lane + 64] = o1;
    outb[lane] = f2b(o0); outb[lane + 64] = f2b(o1);
}

// ---------------- weight prep: cast to bf16 in MFMA FRAGMENT ORDER ----------------
// elem for (frag f, ktile kt, lane, j) at ((kt*F + f)*64 + lane)*8 + j,
// sourcing W[k][n] with n = f*16 + (lane&15), k = kt*32 + (lane>>4)*8 + j.
__global__ void prep_weights(const float* __restrict__ Wmsg_c, const float* __restrict__ Wmsg_v,
                             const float* __restrict__ Wns_c,  const float* __restrict__ Wns_v,
                             const float* __restrict__ Wg_c, const float* __restrict__ Ug_c,
                             const float* __restrict__ Wg_v, const float* __restrict__ Ug_v,
                             unsigned short* __restrict__ Fmsg_c, unsigned short* __restrict__ Fmsg_v,
                             unsigned short* __restrict__ Fns_c,  unsigned short* __restrict__ Fns_v,
                             unsigned short* __restrict__ Fcat_c, unsigned short* __restrict__ Fuh_c,
                             unsigned short* __restrict__ Fcat_v, unsigned short* __restrict__ Fuh_v) {
    int idx = blockIdx.x * blockDim.x + threadIdx.x;
    const int S1 = 4 * 32768;              // msg_c, msg_v, ns_c, ns_v  (F=8, KT=8, ld=128)
    const int S2 = S1 + 2 * 98304;         // cat_c, cat_v              (F=24, KT=8, ld=384)
    const int S3 = S2 + 2 * 16384;         // uh_c, uh_v                (F=8, KT=4, col+256)
    if (idx < S1) {
        int seg = idx >> 15, t = idx & 32767;
        const float* W = (seg == 0) ? Wmsg_c : (seg == 1) ? Wmsg_v : (seg == 2) ? Wns_c : Wns_v;
        unsigned short* out = (seg == 0) ? Fmsg_c : (seg == 1) ? Fmsg_v : (seg == 2) ? Fns_c : Fns_v;
        int j = t & 7, lane = (t >> 3) & 63, t2 = t >> 9;
        int f = t2 & 7, kt = t2 >> 3;
        int n = f * 16 + (lane & 15), k = kt * 32 + (lane >> 4) * 8 + j;
        out[t] = f2b(W[(size_t)k * 128 + n]);
    } else if (idx < S2) {
        int q = idx - S1;
        int seg = q / 98304, t = q - seg * 98304;
        const float* Wg = seg ? Wg_v : Wg_c;
        const float* Ug = seg ? Ug_v : Ug_c;
        unsigned short* out = seg ? Fcat_v : Fcat_c;
        int j = t & 7, lane = (t >> 3) & 63, t2 = t >> 9;
        int f = t2 % 24, kt = t2 / 24;
        int n = f * 16 + (lane & 15), k = kt * 32 + (lane >> 4) * 8 + j;
        out[t] = f2b((k < 128) ? Ug[(size_t)k * 384 + n] : Wg[(size_t)(k - 128) * 384 + n]);
    } else if (idx < S3) {
        int q = idx - S2;
        int seg = q >> 14, t = q & 16383;
        const float* Ug = seg ? Ug_v : Ug_c;
        unsigned short* out = seg ? Fuh_v : Fuh_c;
        int j = t & 7, lane = (t >> 3) & 63, t2 = t >> 9;
        int f = t2 & 7, kt = t2 >> 3;
        int n = f * 16 + (lane & 15), k = kt * 32 + (lane >> 4) * 8 + j;
        out[t] = f2b(Ug[(size_t)k * 384 + 256 + n]);
    }
}

// ---------------- CSR build (once per call) ----------------
__global__ void zero_int_kernel(int* __restrict__ p, int n) {
    int i = blockIdx.x * blockDim.x + threadIdx.x;
    if (i < n) p[i] = 0;
}
__global__ void hist_kernel(const int* __restrict__ tgt_c, const int* __restrict__ tgt_v,
                            int* __restrict__ cnt_c, int* __restrict__ cnt_v) {
    int e = blockIdx.x * blockDim.x + threadIdx.x;
    if (e >= NE) return;
    atomicAdd(&cnt_c[tgt_c[e]], 1);
    atomicAdd(&cnt_v[tgt_v[e]], 1);
}
__launch_bounds__(1024)
__global__ void scan_kernel(const int* __restrict__ cnt, int* __restrict__ rowptr, int n) {
    __shared__ int part[1024];
    int t = threadIdx.x;
    int chunk = (n + 1023) >> 10;
    int base = t * chunk;
    int s = 0;
    for (int i = 0; i < chunk; i++) { int idx = base + i; if (idx < n) s += cnt[idx]; }
    part[t] = s;
    __syncthreads();
    for (int off = 1; off < 1024; off <<= 1) {
        int u = (t >= off) ? part[t - off] : 0;
        __syncthreads();
        part[t] += u;
        __syncthreads();
    }
    int run = part[t] - s;  // exclusive offset
    for (int i = 0; i < chunk; i++) {
        int idx = base + i;
        if (idx < n) { rowptr[idx] = run; run += cnt[idx]; }
    }
    if (t == 0) rowptr[n] = part[1023];
}
// srcs_c = v2c_src reordered so that edges targeting check node c are contiguous (CSR values)
__global__ void fill_kernel(const int* __restrict__ tgt_c, const int* __restrict__ tgt_v,
                            const int* __restrict__ src_c, const int* __restrict__ src_v,
                            const int* __restrict__ rp_c, const int* __restrict__ rp_v,
                            int* __restrict__ fill_c, int* __restrict__ fill_v,
                            int* __restrict__ srcs_c, int* __restrict__ srcs_v) {
    int e = blockIdx.x * blockDim.x + threadIdx.x;
    if (e >= NE) return;
    int tc = tgt_c[e];
    srcs_c[rp_c[tc] + atomicAdd(&fill_c[tc], 1)] = src_c[e];
    int tv = tgt_v[e];
    srcs_v[rp_v[tv] + atomicAdd(&fill_v[tv], 1)] = src_v[e];
}

// ---------------- P/Q init: P = h @ Wmsg_other[:128], Q = h @ Wmsg_own[128:] + b ----------------
// c-blocks (bid<NCB): Pc = hc@Wmsg_v_top, Qc = hc@Wmsg_c_bot + bmsg_c.
// v-blocks:           Pv = hv@Wmsg_c_top, Qv = hv@Wmsg_v_bot + bmsg_v.
__launch_bounds__(256)
__global__ void pq_init(const unsigned short* __restrict__ hcb, const unsigned short* __restrict__ hvb,
                        const unsigned short* __restrict__ Fmsg_c, const unsigned short* __restrict__ Fmsg_v,
                        const float* __restrict__ bmsg_c, const float* __restrict__ bmsg_v,
                        float* __restrict__ Pv_w, float* __restrict__ Qc_w,
                        float* __restrict__ Pc_w, float* __restrict__ Qv_w) {
    __shared__ unsigned short sA[32 * 136];
    const int bid = blockIdx.x;
    const int isV = (bid >= NCB) ? 1 : 0;
    const int blockM = (isV ? (bid - NCB) : bid) * 32;
    const unsigned short* hb = isV ? hvb : hcb;
    const unsigned short* FP = isV ? Fmsg_c : Fmsg_v;   // P uses the OTHER direction's top half
    const unsigned short* FQ = isV ? Fmsg_v : Fmsg_c;   // Q uses own direction's bottom half
    const float* bq = isV ? bmsg_v : bmsg_c;
    float* Pw = isV ? Pv_w : Pc_w;
    float* Qw = isV ? Qv_w : Qc_w;

    const int tid = threadIdx.x;
    const int lane = tid & 63, wave = tid >> 6;
    const int quad = lane >> 4, l16 = lane & 15;
    {
        int r = tid >> 3, c = tid & 7;
        *(s8v*)&sA[r * 136 + c * 16]     = *(const s8v*)&hb[(size_t)(blockM + r) * Hdim + c * 16];
        *(s8v*)&sA[r * 136 + c * 16 + 8] = *(const s8v*)&hb[(size_t)(blockM + r) * Hdim + c * 16 + 8];
    }
    __syncthreads();

    f4v accP[2][2], accQ[2][2];   // [mt][u]
    #pragma unroll
    for (int mt = 0; mt < 2; mt++)
        #pragma unroll
        for (int u = 0; u < 2; u++) { accP[mt][u] = (f4v){0.f,0.f,0.f,0.f}; accQ[mt][u] = (f4v){0.f,0.f,0.f,0.f}; }

    #pragma unroll
    for (int kt = 0; kt < 4; kt++) {
        s8v a0 = *(const s8v*)&sA[l16 * 136 + kt * 32 + quad * 8];
        s8v a1 = *(const s8v*)&sA[(16 + l16) * 136 + kt * 32 + quad * 8];
        #pragma unroll
        for (int u = 0; u < 2; u++) {
            int ct = wave * 2 + u;
            s8v bp = *(const s8v*)&FP[((size_t)(kt * 8 + ct) * 64 + lane) * 8];
            s8v bqv = *(const s8v*)&FQ[((size_t)((kt + 4) * 8 + ct) * 64 + lane) * 8];
            accP[0][u] = __builtin_amdgcn_mfma_f32_16x16x32_bf16(a0, bp, accP[0][u], 0, 0, 0);
            accP[1][u] = __builtin_amdgcn_mfma_f32_16x16x32_bf16(a1, bp, accP[1][u], 0, 0, 0);
            accQ[0][u] = __builtin_amdgcn_mfma_f32_16x16x32_bf16(a0, bqv, accQ[0][u], 0, 0, 0);
            accQ[1][u] = __builtin_amdgcn_mfma_f32_16x16x32_bf16(a1, bqv, accQ[1][u], 0, 0, 0);
        }
    }
    #pragma unroll
    for (int u = 0; u < 2; u++) {
        int col = (wave * 2 + u) * 16 + l16;
        float qbias = bq[col];
        #pragma unroll
        for (int mt = 0; mt < 2; mt++)
            #pragma unroll
            for (int reg = 0; reg < 4; reg++) {
                int row = blockM + mt * 16 + quad * 4 + reg;
                Pw[(size_t)row * Hdim + col] = accP[mt][u][reg];
                Qw[(size_t)row * Hdim + col] = accQ[mt][u][reg] + qbias;
            }
    }
}

// ---------------- fused per-iteration node kernel ----------------
// One dispatch updates BOTH node types (they're independent given precomputed P/Q).
// Per 32-row block: stage h(bf16) -> CSR gather-sum of ELU(P[src]+Q[node]) -> ns GEMM+ELU ->
// GRU gates GEMM -> GRU epilogue -> (optionally) next-iteration P/Q GEMMs.
__launch_bounds__(256)
__global__ void node_fused(float* __restrict__ hc, float* __restrict__ hv,
                           unsigned short* __restrict__ hcb, unsigned short* __restrict__ hvb,
                           const int* __restrict__ rp_c, const int* __restrict__ rp_v,
                           const int* __restrict__ srcs_c, const int* __restrict__ srcs_v,
                           const float* __restrict__ Pv_r, const float* __restrict__ Qc_r,
                           const float* __restrict__ Pc_r, const float* __restrict__ Qv_r,
                           float* __restrict__ Pv_w, float* __restrict__ Qc_w,
                           float* __restrict__ Pc_w, float* __restrict__ Qv_w,
                           const unsigned short* __restrict__ Fns_c, const float* __restrict__ bns_c,
                           const unsigned short* __restrict__ Fns_v, const float* __restrict__ bns_v,
                           const unsigned short* __restrict__ Fcat_c, const unsigned short* __restrict__ Fuh_c,
                           const unsigned short* __restrict__ Fcat_v, const unsigned short* __restrict__ Fuh_v,
                           const float* __restrict__ bg_c, const float* __restrict__ bg_v,
                           const unsigned short* __restrict__ Fmsg_c, const unsigned short* __restrict__ Fmsg_v,
                           const float* __restrict__ bmsg_c, const float* __restrict__ bmsg_v,
                           int do_pq) {
    __shared__ unsigned short sA[32 * 264];   // [32 rows][256 k] stride 264 (16.9 KB)
    const int bid = blockIdx.x;
    const int isV = (bid >= NCB) ? 1 : 0;
    const int blockM = (isV ? (bid - NCB) : bid) * 32;
    float* h = isV ? hv : hc;
    unsigned short* hb = isV ? hvb : hcb;
    const int* rp = isV ? rp_v : rp_c;
    const int* srcs = isV ? srcs_v : srcs_c;
    const float* Pr = isV ? Pc_r : Pv_r;      // messages into v come from c sources, and vice versa
    const float* Qr = isV ? Qv_r : Qc_r;
    const unsigned short* Fns = isV ? Fns_v : Fns_c;
    const float* bns = isV ? bns_v : bns_c;
    const unsigned short* Fcat = isV ? Fcat_v : Fcat_c;
    const unsigned short* Fuh = isV ? Fuh_v : Fuh_c;
    const float* bg = isV ? bg_v : bg_c;
    const unsigned short* FP = isV ? Fmsg_c : Fmsg_v;
    const unsigned short* FQ = isV ? Fmsg_v : Fmsg_c;
    const float* bq = isV ? bmsg_v : bmsg_c;
    float* Pw = isV ? Pv_w : Pc_w;
    float* Qw = isV ? Qv_w : Qc_w;

    const int tid = threadIdx.x;
    const int lane = tid & 63, wave = tid >> 6;
    const int quad = lane >> 4, l16 = lane & 15;

    // ---- stage h (bf16) into sA[:,0:128) and gather-sum ELU(P[src]+Q[node]) into sA[:,128:256) ----
    {
        const int r = tid >> 3, c = tid & 7;        // 32 rows x 8 chunks of 16 cols
        const int node = blockM + r;
        *(s8v*)&sA[r * 264 + c * 16]     = *(const s8v*)&hb[(size_t)node * Hdim + c * 16];
        *(s8v*)&sA[r * 264 + c * 16 + 8] = *(const s8v*)&hb[(size_t)node * Hdim + c * 16 + 8];

        f4v accv[4], qv[4];
        const f4v* q4 = (const f4v*)(Qr + (size_t)node * Hdim + c * 16);
        #pragma unroll
        for (int k = 0; k < 4; k++) { qv[k] = q4[k]; accv[k] = (f4v){0.f,0.f,0.f,0.f}; }
        const int b0 = rp[node], e0 = rp[node + 1];
        for (int j = b0; j < e0; j++) {
            const f4v* p4 = (const f4v*)(Pr + (size_t)srcs[j] * Hdim + c * 16);
            #pragma unroll
            for (int k = 0; k < 4; k++) {
                f4v x = p4[k] + qv[k];
                #pragma unroll
                for (int i = 0; i < 4; i++) accv[k][i] += elu_f(x[i]);
            }
        }
        s8v w0, w1;
        #pragma unroll
        for (int i = 0; i < 4; i++) {
            w0[i]     = (short)f2b(accv[0][i]); w0[i + 4] = (short)f2b(accv[1][i]);
            w1[i]     = (short)f2b(accv[2][i]); w1[i + 4] = (short)f2b(accv[3][i]);
        }
        *(s8v*)&sA[r * 264 + 128 + c * 16]     = w0;
        *(s8v*)&sA[r * 264 + 128 + c * 16 + 8] = w1;
    }
    __syncthreads();

    // ---- phase A: upd = ELU([h|agg] @ Wns + bns); wave handles col-tiles {2w,2w+1} ----
    f4v accA[2][2];   // [mt][u]
    #pragma unroll
    for (int mt = 0; mt < 2; mt++)
        #pragma unroll
        for (int u = 0; u < 2; u++) accA[mt][u] = (f4v){0.f,0.f,0.f,0.f};
    #pragma unroll
    for (int kt = 0; kt < 8; kt++) {
        s8v a0 = *(const s8v*)&sA[l16 * 264 + kt * 32 + quad * 8];
        s8v a1 = *(const s8v*)&sA[(16 + l16) * 264 + kt * 32 + quad * 8];
        #pragma unroll
        for (int u = 0; u < 2; u++) {
            s8v b = *(const s8v*)&Fns[((size_t)(kt * 8 + wave * 2 + u) * 64 + lane) * 8];
            accA[0][u] = __builtin_amdgcn_mfma_f32_16x16x32_bf16(a0, b, accA[0][u], 0, 0, 0);
            accA[1][u] = __builtin_amdgcn_mfma_f32_16x16x32_bf16(a1, b, accA[1][u], 0, 0, 0);
        }
    }
    float updv[2][2][4];   // [u][mt][reg]
    #pragma unroll
    for (int u = 0; u < 2; u++) {
        int col = (wave * 2 + u) * 16 + l16;
        float bb = bns[col];
        #pragma unroll
        for (int mt = 0; mt < 2; mt++)
            #pragma unroll
            for (int reg = 0; reg < 4; reg++)
                updv[u][mt][reg] = elu_f(accA[mt][u][reg] + bb);
    }
    __syncthreads();   // everyone done reading agg region
    #pragma unroll
    for (int u = 0; u < 2; u++) {
        int col = (wave * 2 + u) * 16 + l16;
        #pragma unroll
        for (int mt = 0; mt < 2; mt++)
            #pragma unroll
            for (int reg = 0; reg < 4; reg++)
                sA[(mt * 16 + quad * 4 + reg) * 264 + 128 + col] = f2b(updv[u][mt][reg]);
    }
    __syncthreads();

    // ---- phase B: GRU gates; wave handles col-groups j in {2w,2w+1} ----
    float hnv[2][2][4];   // [u][mt][reg]
    #pragma unroll
    for (int u = 0; u < 2; u++) {
        const int j = wave * 2 + u;
        f4v sZ[2], sR[2], sH[2], hH[2];
        #pragma unroll
        for (int mt = 0; mt < 2; mt++) {
            sZ[mt] = (f4v){0.f,0.f,0.f,0.f}; sR[mt] = (f4v){0.f,0.f,0.f,0.f};
            sH[mt] = (f4v){0.f,0.f,0.f,0.f}; hH[mt] = (f4v){0.f,0.f,0.f,0.f};
        }
        #pragma unroll
        for (int kt = 0; kt < 8; kt++) {
            s8v a0 = *(const s8v*)&sA[l16 * 264 + kt * 32 + quad * 8];
            s8v a1 = *(const s8v*)&sA[(16 + l16) * 264 + kt * 32 + quad * 8];
            s8v bz = *(const s8v*)&Fcat[((size_t)(kt * 24 + j) * 64 + lane) * 8];
            s8v br = *(const s8v*)&Fcat[((size_t)(kt * 24 + 8 + j) * 64 + lane) * 8];
            s8v bh = *(const s8v*)&Fcat[((size_t)(kt * 24 + 16 + j) * 64 + lane) * 8];
            sZ[0] = __builtin_amdgcn_mfma_f32_16x16x32_bf16(a0, bz, sZ[0], 0, 0, 0);
            sZ[1] = __builtin_amdgcn_mfma_f32_16x16x32_bf16(a1, bz, sZ[1], 0, 0, 0);
            sR[0] = __builtin_amdgcn_mfma_f32_16x16x32_bf16(a0, br, sR[0], 0, 0, 0);
            sR[1] = __builtin_amdgcn_mfma_f32_16x16x32_bf16(a1, br, sR[1], 0, 0, 0);
            sH[0] = __builtin_amdgcn_mfma_f32_16x16x32_bf16(a0, bh, sH[0], 0, 0, 0);
            sH[1] = __builtin_amdgcn_mfma_f32_16x16x32_bf16(a1, bh, sH[1], 0, 0, 0);
            if (kt < 4) {
                s8v bu = *(const s8v*)&Fuh[((size_t)(kt * 8 + j) * 64 + lane) * 8];
                hH[0] = __builtin_amdgcn_mfma_f32_16x16x32_bf16(a0, bu, hH[0], 0, 0, 0);
                hH[1] = __builtin_amdgcn_mfma_f32_16x16x32_bf16(a1, bu, hH[1], 0, 0, 0);
            }
        }
        const int t = j * 16 + l16;
        float bz2 = bg[t]       + bg[384 + t];
        float br2 = bg[128 + t] + bg[512 + t];
        float b0h = bg[256 + t];
        float b1h = bg[640 + t];
        #pragma unroll
        for (int mt = 0; mt < 2; mt++)
            #pragma unroll
            for (int reg = 0; reg < 4; reg++) {
                int row = blockM + mt * 16 + quad * 4 + reg;
                float z = sigm_f(sZ[mt][reg] + bz2);
                float rr = sigm_f(sR[mt][reg] + br2);
                float hh = tanhf((sH[mt][reg] - hH[mt][reg] + b0h) + rr * (hH[mt][reg] + b1h));
                float hold = h[(size_t)row * Hdim + t];
                float hn = z * hold + (1.0f - z) * hh;
                h[(size_t)row * Hdim + t] = hn;
                hb[(size_t)row * Hdim + t] = f2b(hn);
                hnv[u][mt][reg] = hn;
            }
    }

    if (!do_pq) return;

    __syncthreads();   // everyone done reading old h in sA[:,0:128)
    #pragma unroll
    for (int u = 0; u < 2; u++) {
        int col = (wave * 2 + u) * 16 + l16;
        #pragma unroll
        for (int mt = 0; mt < 2; mt++)
            #pragma unroll
            for (int reg = 0; reg < 4; reg++)
                sA[(mt * 16 + quad * 4 + reg) * 264 + col] = f2b(hnv[u][mt][reg]);
    }
    __syncthreads();

    // ---- phase C: next-iteration P/Q from new h (K=128) ----
    f4v accP[2][2], accQ[2][2];   // [mt][u]
    #pragma unroll
    for (int mt = 0; mt < 2; mt++)
        #pragma unroll
        for (int u = 0; u < 2; u++) { accP[mt][u] = (f4v){0.f,0.f,0.f,0.f}; accQ[mt][u] = (f4v){0.f,0.f,0.f,0.f}; }
    #pragma unroll
    for (int kt = 0; kt < 4; kt++) {
        s8v a0 = *(const s8v*)&sA[l16 * 264 + kt * 32 + quad * 8];
        s8v a1 = *(const s8v*)&sA[(16 + l16) * 264 + kt * 32 + quad * 8];
        #pragma unroll
        for (int u = 0; u < 2; u++) {
            int ct = wave * 2 + u;
            s8v bp = *(const s8v*)&FP[((size_t)(kt * 8 + ct) * 64 + lane) * 8];
            s8v bqv = *(const s8v*)&FQ[((size_t)((kt + 4) * 8 + ct) * 64 + lane) * 8];
            accP[0][u] = __builtin_amdgcn_mfma_f32_16x16x32_bf16(a0, bp, accP[0][u], 0, 0, 0);
            accP[1][u] = __builtin_amdgcn_mfma_f32_16x16x32_bf16(a1, bp, accP[1][u], 0, 0, 0);
            accQ[0][u] = __builtin_amdgcn_mfma_f32_16x16x32_bf16(a0, bqv, accQ[0][u], 0, 0, 0);
            accQ[1][u] = __builtin_amdgcn_mfma_f32_16x16x32_bf16(a1, bqv, accQ[1][u], 0, 0, 0);
        }
    }
    #pragma unroll
    for (int u = 0; u < 2; u++) {
        int col = (wave * 2 + u) * 16 + l16;
        float qbias = bq[col];
        #pragma unroll
        for (int mt = 0; mt < 2; mt++)
            #pragma unroll
            for (int reg = 0; reg < 4; reg++) {
                int row = blockM + mt * 16 + quad * 4 + reg;
                Pw[(size_t)row * Hdim + col] = accP[mt][u][reg];
                Qw[(size_t)row * Hdim + col] = accQ[mt][u][reg] + qbias;
            }
    }
}

// ---------------- final: out[i] = dot(hv[i], Wf) + bf ----------------
__global__ void final_kernel(const float* __restrict__ hv, const float* __restrict__ Wf,
                             const float* __restrict__ bf, float* __restrict__ out) {
    int node = blockIdx.x * 4 + (threadIdx.x >> 6);
    int lane = threadIdx.x & 63;
    const float* row = hv + (size_t)node * Hdim;
    float s = row[lane] * Wf[lane] + row[lane + 64] * Wf[lane + 64];
    #pragma unroll
    for (int off = 32; off > 0; off >>= 1) s += __shfl_xor(s, off);
    if (lane == 0) out[node] = s + bf[0];
}

extern "C" void kernel_launch(void* const* d_in, const int* in_sizes, int n_in,
                              void* d_out, int out_size, void* d_ws, size_t ws_size,
                              hipStream_t stream) {
    const float* cf      = (const float*)d_in[0];
    const float* vf      = (const float*)d_in[1];
    const int*   c2v_src = (const int*)d_in[2];
    const int*   c2v_tgt = (const int*)d_in[3];
    const int*   v2c_src = (const int*)d_in[4];
    const int*   v2c_tgt = (const int*)d_in[5];
    const float* Wc_in   = (const float*)d_in[6];
    const float* bc_in   = (const float*)d_in[7];
    const float* Wv_in   = (const float*)d_in[8];
    const float* bv_in   = (const float*)d_in[9];
    const float* gc_ln   = (const float*)d_in[10];
    const float* bc_ln   = (const float*)d_in[11];
    const float* gv_ln   = (const float*)d_in[12];
    const float* bv_ln   = (const float*)d_in[13];
    const float* Wmsg_c  = (const float*)d_in[14];
    const float* bmsg_c  = (const float*)d_in[15];
    const float* Wmsg_v  = (const float*)d_in[16];
    const float* bmsg_v  = (const float*)d_in[17];
    const float* Wns_c   = (const float*)d_in[18];
    const float* bns_c   = (const float*)d_in[19];
    const float* Wns_v   = (const float*)d_in[20];
    const float* bns_v   = (const float*)d_in[21];
    const float* Wg_c    = (const float*)d_in[22];
    const float* Ug_c    = (const float*)d_in[23];
    const float* bg_c    = (const float*)d_in[24];
    const float* Wg_v    = (const float*)d_in[25];
    const float* Ug_v    = (const float*)d_in[26];
    const float* bg_v    = (const float*)d_in[27];
    const float* Wf      = (const float*)d_in[28];
    const float* bf      = (const float*)d_in[29];
    float* out = (float*)d_out;

    // ---- workspace carve (256B-aligned) ----
    char* p = (char*)d_ws;
    #define CARVE(name, type, count) type* name = (type*)p; p += (((size_t)(count) * sizeof(type)) + 255) & ~(size_t)255;
    CARVE(hc,     float, NCn * Hdim)
    CARVE(hv,     float, NVn * Hdim)
    CARVE(hc_b,   unsigned short, NCn * Hdim)
    CARVE(hv_b,   unsigned short, NVn * Hdim)
    CARVE(Pv0,    float, NVn * Hdim)
    CARVE(Qc0,    float, NCn * Hdim)
    CARVE(Pc0,    float, NCn * Hdim)
    CARVE(Qv0,    float, NVn * Hdim)
    CARVE(Pv1,    float, NVn * Hdim)
    CARVE(Qc1,    float, NCn * Hdim)
    CARVE(Pc1,    float, NCn * Hdim)
    CARVE(Qv1,    float, NVn * Hdim)
    CARVE(Fmsg_c, unsigned short, 32768)
    CARVE(Fmsg_v, unsigned short, 32768)
    CARVE(Fns_c,  unsigned short, 32768)
    CARVE(Fns_v,  unsigned short, 32768)
    CARVE(Fcat_c, unsigned short, 98304)
    CARVE(Fuh_c,  unsigned short, 16384)
    CARVE(Fcat_v, unsigned short, 98304)
    CARVE(Fuh_v,  unsigned short, 16384)
    CARVE(rp_c,  int, NCn + 8)
    CARVE(rp_v,  int, NVn + 8)
    CARVE(srcs_c, int, NE)
    CARVE(srcs_v, int, NE)
    CARVE(cnts,  int, 48000)
    #undef CARVE
    int* cnt_c  = cnts;
    int* cnt_v  = cnts + NCn;
    int* fill_c = cnts + NCn + NVn;
    int* fill_v = cnts + 2 * NCn + NVn;

    // ---- once-per-call prep ----
    prep_weights<<<(4 * 32768 + 2 * 98304 + 2 * 16384 + 255) / 256, 256, 0, stream>>>(
        Wmsg_c, Wmsg_v, Wns_c, Wns_v, Wg_c, Ug_c, Wg_v, Ug_v,
        Fmsg_c, Fmsg_v, Fns_c, Fns_v, Fcat_c, Fuh_c, Fcat_v, Fuh_v);
    zero_int_kernel<<<(48000 + 255) / 256, 256, 0, stream>>>(cnts, 48000);
    hist_kernel<<<(NE + 255) / 256, 256, 0, stream>>>(v2c_tgt, c2v_tgt, cnt_c, cnt_v);
    scan_kernel<<<1, 1024, 0, stream>>>(cnt_c, rp_c, NCn);
    scan_kernel<<<1, 1024, 0, stream>>>(cnt_v, rp_v, NVn);
    fill_kernel<<<(NE + 255) / 256, 256, 0, stream>>>(v2c_tgt, c2v_tgt, v2c_src, c2v_src,
                                                      rp_c, rp_v, fill_c, fill_v, srcs_c, srcs_v);
    init_kernel<<<NCn + NVn, 64, 0, stream>>>(cf, vf, Wc_in, bc_in, Wv_in, bv_in,
                                              gc_ln, bc_ln, gv_ln, bv_ln, hc, hv, hc_b, hv_b);
    pq_init<<<NCB + NVB, 256, 0, stream>>>(hc_b, hv_b, Fmsg_c, Fmsg_v, bmsg_c, bmsg_v,
                                           Pv0, Qc0, Pc0, Qv0);

    float* Pv_[2] = {Pv0, Pv1};
    float* Qc_[2] = {Qc0, Qc1};
    float* Pc_[2] = {Pc0, Pc1};
    float* Qv_[2] = {Qv0, Qv1};

    for (int it = 0; it < LITERS; it++) {
        int rd = it & 1, wr = rd ^ 1;
        node_fused<<<NCB + NVB, 256, 0, stream>>>(
            hc, hv, hc_b, hv_b, rp_c, rp_v, srcs_c, srcs_v,
            Pv_[rd], Qc_[rd], Pc_[rd], Qv_[rd],
            Pv_[wr], Qc_[wr], Pc_[wr], Qv_[wr],
            Fns_c, bns_c, Fns_v, bns_v,
            Fcat_c, Fuh_c, Fcat_v, Fuh_v, bg_c, bg_v,
            Fmsg_c, Fmsg_v, bmsg_c, bmsg_v,
            (it < LITERS - 1) ? 1 : 0);
    }

    final_kernel<<<NVn / 4, 256, 0, stream>>>(hv, Wf, bf, out);
}

// Round 2
// 626.123 us; speedup vs baseline: 1.2518x; 1.2518x over previous
//
#include <hip/hip_runtime.h>
#include <hip/hip_bf16.h>
#include <math.h>

#define Hdim 128
#define NCn  8000
#define NVn  16000
#define NE   60000
#define LITERS 10
#define NCB16 500    // c-blocks in node_fused (16 rows)
#define NVB16 1000   // v-blocks in node_fused
#define NCB32 250    // c-blocks in pq_init (32 rows)
#define NVB32 500

typedef __attribute__((ext_vector_type(8))) short s8v;   // 8 x bf16 (4 VGPRs)
typedef __attribute__((ext_vector_type(4))) float f4v;   // MFMA acc / float4

__device__ __forceinline__ float elu_f(float x) { return x > 0.0f ? x : (expf(x) - 1.0f); }
__device__ __forceinline__ float sigm_f(float x) { return 1.0f / (1.0f + expf(-x)); }
__device__ __forceinline__ unsigned short f2b(float x) {
    __hip_bfloat16 h = __float2bfloat16(x); return *(unsigned short*)&h;
}
__device__ __forceinline__ float b2f(unsigned short u) {
    __hip_bfloat16 h; *(unsigned short*)&h = u; return __bfloat162float(h);
}

// ---------------- init: h = LN(0.1*f*W_in + b_in), fp32 + bf16 mirror ----------------
__global__ void init_kernel(const float* __restrict__ cf, const float* __restrict__ vf,
                            const float* __restrict__ Wc, const float* __restrict__ bc,
                            const float* __restrict__ Wv, const float* __restrict__ bv,
                            const float* __restrict__ gc, const float* __restrict__ bcl,
                            const float* __restrict__ gv, const float* __restrict__ bvl,
                            float* __restrict__ hc, float* __restrict__ hv,
                            unsigned short* __restrict__ hcb, unsigned short* __restrict__ hvb) {
    int node = blockIdx.x;
    int lane = threadIdx.x;  // 64 threads, 2 elements each
    const float *Win, *bin, *g, *bl;
    float f;
    float* outp;
    unsigned short* outb;
    if (node < NCn) {
        f = cf[node]; Win = Wc; bin = bc; g = gc; bl = bcl;
        outp = hc + (size_t)node * Hdim; outb = hcb + (size_t)node * Hdim;
    } else {
        int n2 = node - NCn;
        f = vf[n2]; Win = Wv; bin = bv; g = gv; bl = bvl;
        outp = hv + (size_t)n2 * Hdim; outb = hvb + (size_t)n2 * Hdim;
    }
    f *= 0.1f;
    float x0 = f * Win[lane] + bin[lane];
    float x1 = f * Win[lane + 64] + bin[lane + 64];
    float s = x0 + x1;
    float sq = x0 * x0 + x1 * x1;
    #pragma unroll
    for (int off = 32; off > 0; off >>= 1) {
        s += __shfl_xor(s, off);
        sq += __shfl_xor(sq, off);
    }
    float m = s * (1.0f / 128.0f);
    float v = sq * (1.0f / 128.0f) - m * m;
    float inv = 1.0f / sqrtf(v + 1e-6f);
    float o0 = g[lane]      * (x0 - m) * inv + bl[lane];
    float o1 = g[lane + 64] * (x1 - m) * inv + bl[lane + 64];
    outp[lane] = o0; outp[lane + 64] = o1;
    outb[lane] = f2b(o0); outb[lane + 64] = f2b(o1);
}

// ---------------- weight prep: cast to bf16 in MFMA FRAGMENT ORDER ----------------
// elem for (frag f, ktile kt, lane, j) at ((kt*F + f)*64 + lane)*8 + j,
// sourcing W[k][n] with n = f*16 + (lane&15), k = kt*32 + (lane>>4)*8 + j.
__global__ void prep_weights(const float* __restrict__ Wmsg_c, const float* __restrict__ Wmsg_v,
                             const float* __restrict__ Wns_c,  const float* __restrict__ Wns_v,
                             const float* __restrict__ Wg_c, const float* __restrict__ Ug_c,
                             const float* __restrict__ Wg_v, const float* __restrict__ Ug_v,
                             unsigned short* __restrict__ Fmsg_c, unsigned short* __restrict__ Fmsg_v,
                             unsigned short* __restrict__ Fns_c,  unsigned short* __restrict__ Fns_v,
                             unsigned short* __restrict__ Fcat_c, unsigned short* __restrict__ Fuh_c,
                             unsigned short* __restrict__ Fcat_v, unsigned short* __restrict__ Fuh_v) {
    int idx = blockIdx.x * blockDim.x + threadIdx.x;
    const int S1 = 4 * 32768;              // msg_c, msg_v, ns_c, ns_v  (F=8, KT=8, ld=128)
    const int S2 = S1 + 2 * 98304;         // cat_c, cat_v              (F=24, KT=8, ld=384)
    const int S3 = S2 + 2 * 16384;         // uh_c, uh_v                (F=8, KT=4, col+256)
    if (idx < S1) {
        int seg = idx >> 15, t = idx & 32767;
        const float* W = (seg == 0) ? Wmsg_c : (seg == 1) ? Wmsg_v : (seg == 2) ? Wns_c : Wns_v;
        unsigned short* out = (seg == 0) ? Fmsg_c : (seg == 1) ? Fmsg_v : (seg == 2) ? Fns_c : Fns_v;
        int j = t & 7, lane = (t >> 3) & 63, t2 = t >> 9;
        int f = t2 & 7, kt = t2 >> 3;
        int n = f * 16 + (lane & 15), k = kt * 32 + (lane >> 4) * 8 + j;
        out[t] = f2b(W[(size_t)k * 128 + n]);
    } else if (idx < S2) {
        int q = idx - S1;
        int seg = q / 98304, t = q - seg * 98304;
        const float* Wg = seg ? Wg_v : Wg_c;
        const float* Ug = seg ? Ug_v : Ug_c;
        unsigned short* out = seg ? Fcat_v : Fcat_c;
        int j = t & 7, lane = (t >> 3) & 63, t2 = t >> 9;
        int f = t2 % 24, kt = t2 / 24;
        int n = f * 16 + (lane & 15), k = kt * 32 + (lane >> 4) * 8 + j;
        out[t] = f2b((k < 128) ? Ug[(size_t)k * 384 + n] : Wg[(size_t)(k - 128) * 384 + n]);
    } else if (idx < S3) {
        int q = idx - S2;
        int seg = q >> 14, t = q & 16383;
        const float* Ug = seg ? Ug_v : Ug_c;
        unsigned short* out = seg ? Fuh_v : Fuh_c;
        int j = t & 7, lane = (t >> 3) & 63, t2 = t >> 9;
        int f = t2 & 7, kt = t2 >> 3;
        int n = f * 16 + (lane & 15), k = kt * 32 + (lane >> 4) * 8 + j;
        out[t] = f2b(Ug[(size_t)k * 384 + 256 + n]);
    }
}

// ---------------- CSR build (once per call) ----------------
__global__ void zero_int_kernel(int* __restrict__ p, int n) {
    int i = blockIdx.x * blockDim.x + threadIdx.x;
    if (i < n) p[i] = 0;
}
__global__ void hist_kernel(const int* __restrict__ tgt_c, const int* __restrict__ tgt_v,
                            int* __restrict__ cnt_c, int* __restrict__ cnt_v) {
    int e = blockIdx.x * blockDim.x + threadIdx.x;
    if (e >= NE) return;
    atomicAdd(&cnt_c[tgt_c[e]], 1);
    atomicAdd(&cnt_v[tgt_v[e]], 1);
}
__launch_bounds__(1024)
__global__ void scan_kernel(const int* __restrict__ cnt, int* __restrict__ rowptr, int n) {
    __shared__ int part[1024];
    int t = threadIdx.x;
    int chunk = (n + 1023) >> 10;
    int base = t * chunk;
    int s = 0;
    for (int i = 0; i < chunk; i++) { int idx = base + i; if (idx < n) s += cnt[idx]; }
    part[t] = s;
    __syncthreads();
    for (int off = 1; off < 1024; off <<= 1) {
        int u = (t >= off) ? part[t - off] : 0;
        __syncthreads();
        part[t] += u;
        __syncthreads();
    }
    int run = part[t] - s;  // exclusive offset
    for (int i = 0; i < chunk; i++) {
        int idx = base + i;
        if (idx < n) { rowptr[idx] = run; run += cnt[idx]; }
    }
    if (t == 0) rowptr[n] = part[1023];
}
// srcs_c = v2c_src reordered so that edges targeting check node c are contiguous (CSR values)
__global__ void fill_kernel(const int* __restrict__ tgt_c, const int* __restrict__ tgt_v,
                            const int* __restrict__ src_c, const int* __restrict__ src_v,
                            const int* __restrict__ rp_c, const int* __restrict__ rp_v,
                            int* __restrict__ fill_c, int* __restrict__ fill_v,
                            int* __restrict__ srcs_c, int* __restrict__ srcs_v) {
    int e = blockIdx.x * blockDim.x + threadIdx.x;
    if (e >= NE) return;
    int tc = tgt_c[e];
    srcs_c[rp_c[tc] + atomicAdd(&fill_c[tc], 1)] = src_c[e];
    int tv = tgt_v[e];
    srcs_v[rp_v[tv] + atomicAdd(&fill_v[tv], 1)] = src_v[e];
}

// ---------------- P/Q init (bf16 out): P = h @ Wmsg_other[:128], Q = h @ Wmsg_own[128:] + b ----
__launch_bounds__(256)
__global__ void pq_init(const unsigned short* __restrict__ hcb, const unsigned short* __restrict__ hvb,
                        const unsigned short* __restrict__ Fmsg_c, const unsigned short* __restrict__ Fmsg_v,
                        const float* __restrict__ bmsg_c, const float* __restrict__ bmsg_v,
                        unsigned short* __restrict__ Pv_w, unsigned short* __restrict__ Qc_w,
                        unsigned short* __restrict__ Pc_w, unsigned short* __restrict__ Qv_w) {
    __shared__ unsigned short sA[32 * 136];
    const int bid = blockIdx.x;
    const int isV = (bid >= NCB32) ? 1 : 0;
    const int blockM = (isV ? (bid - NCB32) : bid) * 32;
    const unsigned short* hb = isV ? hvb : hcb;
    const unsigned short* FP = isV ? Fmsg_c : Fmsg_v;   // P uses the OTHER direction's top half
    const unsigned short* FQ = isV ? Fmsg_v : Fmsg_c;   // Q uses own direction's bottom half
    const float* bq = isV ? bmsg_v : bmsg_c;
    unsigned short* Pw = isV ? Pv_w : Pc_w;
    unsigned short* Qw = isV ? Qv_w : Qc_w;

    const int tid = threadIdx.x;
    const int lane = tid & 63, wave = tid >> 6;
    const int quad = lane >> 4, l16 = lane & 15;
    {
        int r = tid >> 3, c = tid & 7;
        *(s8v*)&sA[r * 136 + c * 16]     = *(const s8v*)&hb[(size_t)(blockM + r) * Hdim + c * 16];
        *(s8v*)&sA[r * 136 + c * 16 + 8] = *(const s8v*)&hb[(size_t)(blockM + r) * Hdim + c * 16 + 8];
    }
    __syncthreads();

    f4v accP[2][2], accQ[2][2];   // [mt][u]
    #pragma unroll
    for (int mt = 0; mt < 2; mt++)
        #pragma unroll
        for (int u = 0; u < 2; u++) { accP[mt][u] = (f4v){0.f,0.f,0.f,0.f}; accQ[mt][u] = (f4v){0.f,0.f,0.f,0.f}; }

    #pragma unroll
    for (int kt = 0; kt < 4; kt++) {
        s8v a0 = *(const s8v*)&sA[l16 * 136 + kt * 32 + quad * 8];
        s8v a1 = *(const s8v*)&sA[(16 + l16) * 136 + kt * 32 + quad * 8];
        #pragma unroll
        for (int u = 0; u < 2; u++) {
            int ct = wave * 2 + u;
            s8v bp = *(const s8v*)&FP[((size_t)(kt * 8 + ct) * 64 + lane) * 8];
            s8v bqv = *(const s8v*)&FQ[((size_t)((kt + 4) * 8 + ct) * 64 + lane) * 8];
            accP[0][u] = __builtin_amdgcn_mfma_f32_16x16x32_bf16(a0, bp, accP[0][u], 0, 0, 0);
            accP[1][u] = __builtin_amdgcn_mfma_f32_16x16x32_bf16(a1, bp, accP[1][u], 0, 0, 0);
            accQ[0][u] = __builtin_amdgcn_mfma_f32_16x16x32_bf16(a0, bqv, accQ[0][u], 0, 0, 0);
            accQ[1][u] = __builtin_amdgcn_mfma_f32_16x16x32_bf16(a1, bqv, accQ[1][u], 0, 0, 0);
        }
    }
    #pragma unroll
    for (int u = 0; u < 2; u++) {
        int col = (wave * 2 + u) * 16 + l16;
        float qbias = bq[col];
        #pragma unroll
        for (int mt = 0; mt < 2; mt++)
            #pragma unroll
            for (int reg = 0; reg < 4; reg++) {
                int row = blockM + mt * 16 + quad * 4 + reg;
                Pw[(size_t)row * Hdim + col] = f2b(accP[mt][u][reg]);
                Qw[(size_t)row * Hdim + col] = f2b(accQ[mt][u][reg] + qbias);
            }
    }
}

// ---------------- fused per-iteration node kernel (16-row blocks) ----------------
// Per 16-row block: stage h(bf16) + MLP-unrolled CSR gather of ELU(P[src]+Q[node]) ->
// ns GEMM+ELU -> GRU gates GEMM -> GRU epilogue -> next-iteration P/Q GEMMs (bf16 out).
__launch_bounds__(256)
__global__ void node_fused(float* __restrict__ hc, float* __restrict__ hv,
                           unsigned short* __restrict__ hcb, unsigned short* __restrict__ hvb,
                           const int* __restrict__ rp_c, const int* __restrict__ rp_v,
                           const int* __restrict__ srcs_c, const int* __restrict__ srcs_v,
                           const unsigned short* __restrict__ Pv_r, const unsigned short* __restrict__ Qc_r,
                           const unsigned short* __restrict__ Pc_r, const unsigned short* __restrict__ Qv_r,
                           unsigned short* __restrict__ Pv_w, unsigned short* __restrict__ Qc_w,
                           unsigned short* __restrict__ Pc_w, unsigned short* __restrict__ Qv_w,
                           const unsigned short* __restrict__ Fns_c, const float* __restrict__ bns_c,
                           const unsigned short* __restrict__ Fns_v, const float* __restrict__ bns_v,
                           const unsigned short* __restrict__ Fcat_c, const unsigned short* __restrict__ Fuh_c,
                           const unsigned short* __restrict__ Fcat_v, const unsigned short* __restrict__ Fuh_v,
                           const float* __restrict__ bg_c, const float* __restrict__ bg_v,
                           const unsigned short* __restrict__ Fmsg_c, const unsigned short* __restrict__ Fmsg_v,
                           const float* __restrict__ bmsg_c, const float* __restrict__ bmsg_v,
                           int do_pq) {
    __shared__ unsigned short sA[16 * 264];   // [16 rows][256 k] stride 264 (8.4 KB)
    const int bid = blockIdx.x;
    const int isV = (bid >= NCB16) ? 1 : 0;
    const int blockM = (isV ? (bid - NCB16) : bid) * 16;
    float* h = isV ? hv : hc;
    unsigned short* hb = isV ? hvb : hcb;
    const int* rp = isV ? rp_v : rp_c;
    const int* srcs = isV ? srcs_v : srcs_c;
    const unsigned short* Pr = isV ? Pc_r : Pv_r;   // messages into v come from c sources, vice versa
    const unsigned short* Qr = isV ? Qv_r : Qc_r;
    const unsigned short* Fns = isV ? Fns_v : Fns_c;
    const float* bns = isV ? bns_v : bns_c;
    const unsigned short* Fcat = isV ? Fcat_v : Fcat_c;
    const unsigned short* Fuh = isV ? Fuh_v : Fuh_c;
    const float* bg = isV ? bg_v : bg_c;
    const unsigned short* FP = isV ? Fmsg_c : Fmsg_v;
    const unsigned short* FQ = isV ? Fmsg_v : Fmsg_c;
    const float* bq = isV ? bmsg_v : bmsg_c;
    unsigned short* Pw = isV ? Pv_w : Pc_w;
    unsigned short* Qw = isV ? Qv_w : Qc_w;

    const int tid = threadIdx.x;
    const int lane = tid & 63, wave = tid >> 6;
    const int quad = lane >> 4, l16 = lane & 15;

    // ---- stage h (bf16) into sA[:,0:128) and gather-sum ELU(P[src]+Q[node]) into sA[:,128:256) ----
    {
        const int r = tid >> 4, c = tid & 15;    // 16 rows x 16 threads; 8 cols (16B bf16) each
        const int node = blockM + r;
        *(s8v*)&sA[r * 264 + c * 8] = *(const s8v*)&hb[(size_t)node * Hdim + c * 8];

        s8v q8 = *(const s8v*)&Qr[(size_t)node * Hdim + c * 8];
        float qf[8], acc[8];
        #pragma unroll
        for (int i = 0; i < 8; i++) { qf[i] = b2f((unsigned short)q8[i]); acc[i] = 0.0f; }

        int j = rp[node];
        const int e0 = rp[node + 1];
        // unroll-4: issue 4 independent P-row loads before any math (MLP)
        for (; j + 4 <= e0; j += 4) {
            int s0 = srcs[j], s1 = srcs[j + 1], s2 = srcs[j + 2], s3 = srcs[j + 3];
            s8v p0 = *(const s8v*)&Pr[(size_t)s0 * Hdim + c * 8];
            s8v p1 = *(const s8v*)&Pr[(size_t)s1 * Hdim + c * 8];
            s8v p2 = *(const s8v*)&Pr[(size_t)s2 * Hdim + c * 8];
            s8v p3 = *(const s8v*)&Pr[(size_t)s3 * Hdim + c * 8];
            #pragma unroll
            for (int i = 0; i < 8; i++) acc[i] += elu_f(b2f((unsigned short)p0[i]) + qf[i]);
            #pragma unroll
            for (int i = 0; i < 8; i++) acc[i] += elu_f(b2f((unsigned short)p1[i]) + qf[i]);
            #pragma unroll
            for (int i = 0; i < 8; i++) acc[i] += elu_f(b2f((unsigned short)p2[i]) + qf[i]);
            #pragma unroll
            for (int i = 0; i < 8; i++) acc[i] += elu_f(b2f((unsigned short)p3[i]) + qf[i]);
        }
        if (j + 2 <= e0) {
            int s0 = srcs[j], s1 = srcs[j + 1];
            s8v p0 = *(const s8v*)&Pr[(size_t)s0 * Hdim + c * 8];
            s8v p1 = *(const s8v*)&Pr[(size_t)s1 * Hdim + c * 8];
            #pragma unroll
            for (int i = 0; i < 8; i++) acc[i] += elu_f(b2f((unsigned short)p0[i]) + qf[i]);
            #pragma unroll
            for (int i = 0; i < 8; i++) acc[i] += elu_f(b2f((unsigned short)p1[i]) + qf[i]);
            j += 2;
        }
        if (j < e0) {
            int s0 = srcs[j];
            s8v p0 = *(const s8v*)&Pr[(size_t)s0 * Hdim + c * 8];
            #pragma unroll
            for (int i = 0; i < 8; i++) acc[i] += elu_f(b2f((unsigned short)p0[i]) + qf[i]);
        }
        s8v w;
        #pragma unroll
        for (int i = 0; i < 8; i++) w[i] = (short)f2b(acc[i]);
        *(s8v*)&sA[r * 264 + 128 + c * 8] = w;
    }
    __syncthreads();

    // ---- phase A: upd = ELU([h|agg] @ Wns + bns); wave handles col-tiles {2w,2w+1} ----
    f4v accA[2];
    accA[0] = (f4v){0.f,0.f,0.f,0.f};
    accA[1] = (f4v){0.f,0.f,0.f,0.f};
    #pragma unroll
    for (int kt = 0; kt < 8; kt++) {
        s8v a = *(const s8v*)&sA[l16 * 264 + kt * 32 + quad * 8];
        #pragma unroll
        for (int u = 0; u < 2; u++) {
            s8v b = *(const s8v*)&Fns[((size_t)(kt * 8 + wave * 2 + u) * 64 + lane) * 8];
            accA[u] = __builtin_amdgcn_mfma_f32_16x16x32_bf16(a, b, accA[u], 0, 0, 0);
        }
    }
    float updv[2][4];
    #pragma unroll
    for (int u = 0; u < 2; u++) {
        int col = (wave * 2 + u) * 16 + l16;
        float bb = bns[col];
        #pragma unroll
        for (int reg = 0; reg < 4; reg++)
            updv[u][reg] = elu_f(accA[u][reg] + bb);
    }
    __syncthreads();   // everyone done reading agg region
    #pragma unroll
    for (int u = 0; u < 2; u++) {
        int col = (wave * 2 + u) * 16 + l16;
        #pragma unroll
        for (int reg = 0; reg < 4; reg++)
            sA[(quad * 4 + reg) * 264 + 128 + col] = f2b(updv[u][reg]);
    }
    __syncthreads();

    // ---- phase B: GRU gates; wave handles col-groups j in {2w,2w+1} ----
    float hnv[2][4];
    #pragma unroll
    for (int u = 0; u < 2; u++) {
        const int j = wave * 2 + u;
        f4v sZ = (f4v){0.f,0.f,0.f,0.f};
        f4v sR = (f4v){0.f,0.f,0.f,0.f};
        f4v sH = (f4v){0.f,0.f,0.f,0.f};
        f4v hH = (f4v){0.f,0.f,0.f,0.f};
        #pragma unroll
        for (int kt = 0; kt < 8; kt++) {
            s8v a = *(const s8v*)&sA[l16 * 264 + kt * 32 + quad * 8];
            s8v bz = *(const s8v*)&Fcat[((size_t)(kt * 24 + j) * 64 + lane) * 8];
            s8v br = *(const s8v*)&Fcat[((size_t)(kt * 24 + 8 + j) * 64 + lane) * 8];
            s8v bh = *(const s8v*)&Fcat[((size_t)(kt * 24 + 16 + j) * 64 + lane) * 8];
            sZ = __builtin_amdgcn_mfma_f32_16x16x32_bf16(a, bz, sZ, 0, 0, 0);
            sR = __builtin_amdgcn_mfma_f32_16x16x32_bf16(a, br, sR, 0, 0, 0);
            sH = __builtin_amdgcn_mfma_f32_16x16x32_bf16(a, bh, sH, 0, 0, 0);
            if (kt < 4) {
                s8v bu = *(const s8v*)&Fuh[((size_t)(kt * 8 + j) * 64 + lane) * 8];
                hH = __builtin_amdgcn_mfma_f32_16x16x32_bf16(a, bu, hH, 0, 0, 0);
            }
        }
        const int t = j * 16 + l16;
        float bz2 = bg[t]       + bg[384 + t];
        float br2 = bg[128 + t] + bg[512 + t];
        float b0h = bg[256 + t];
        float b1h = bg[640 + t];
        #pragma unroll
        for (int reg = 0; reg < 4; reg++) {
            int row = blockM + quad * 4 + reg;
            float z = sigm_f(sZ[reg] + bz2);
            float rr = sigm_f(sR[reg] + br2);
            float hh = tanhf((sH[reg] - hH[reg] + b0h) + rr * (hH[reg] + b1h));
            float hold = h[(size_t)row * Hdim + t];
            float hn = z * hold + (1.0f - z) * hh;
            h[(size_t)row * Hdim + t] = hn;
            hb[(size_t)row * Hdim + t] = f2b(hn);
            hnv[u][reg] = hn;
        }
    }

    if (!do_pq) return;

    __syncthreads();   // everyone done reading old h in sA[:,0:128)
    #pragma unroll
    for (int u = 0; u < 2; u++) {
        int col = (wave * 2 + u) * 16 + l16;
        #pragma unroll
        for (int reg = 0; reg < 4; reg++)
            sA[(quad * 4 + reg) * 264 + col] = f2b(hnv[u][reg]);
    }
    __syncthreads();

    // ---- phase C: next-iteration P/Q from new h (K=128), bf16 out ----
    f4v accP[2], accQ[2];
    accP[0] = (f4v){0.f,0.f,0.f,0.f}; accP[1] = (f4v){0.f,0.f,0.f,0.f};
    accQ[0] = (f4v){0.f,0.f,0.f,0.f}; accQ[1] = (f4v){0.f,0.f,0.f,0.f};
    #pragma unroll
    for (int kt = 0; kt < 4; kt++) {
        s8v a = *(const s8v*)&sA[l16 * 264 + kt * 32 + quad * 8];
        #pragma unroll
        for (int u = 0; u < 2; u++) {
            int ct = wave * 2 + u;
            s8v bp = *(const s8v*)&FP[((size_t)(kt * 8 + ct) * 64 + lane) * 8];
            s8v bqv = *(const s8v*)&FQ[((size_t)((kt + 4) * 8 + ct) * 64 + lane) * 8];
            accP[u] = __builtin_amdgcn_mfma_f32_16x16x32_bf16(a, bp, accP[u], 0, 0, 0);
            accQ[u] = __builtin_amdgcn_mfma_f32_16x16x32_bf16(a, bqv, accQ[u], 0, 0, 0);
        }
    }
    #pragma unroll
    for (int u = 0; u < 2; u++) {
        int col = (wave * 2 + u) * 16 + l16;
        float qbias = bq[col];
        #pragma unroll
        for (int reg = 0; reg < 4; reg++) {
            int row = blockM + quad * 4 + reg;
            Pw[(size_t)row * Hdim + col] = f2b(accP[u][reg]);
            Qw[(size_t)row * Hdim + col] = f2b(accQ[u][reg] + qbias);
        }
    }
}

// ---------------- final: out[i] = dot(hv[i], Wf) + bf ----------------
__global__ void final_kernel(const float* __restrict__ hv, const float* __restrict__ Wf,
                             const float* __restrict__ bf, float* __restrict__ out) {
    int node = blockIdx.x * 4 + (threadIdx.x >> 6);
    int lane = threadIdx.x & 63;
    const float* row = hv + (size_t)node * Hdim;
    float s = row[lane] * Wf[lane] + row[lane + 64] * Wf[lane + 64];
    #pragma unroll
    for (int off = 32; off > 0; off >>= 1) s += __shfl_xor(s, off);
    if (lane == 0) out[node] = s + bf[0];
}

extern "C" void kernel_launch(void* const* d_in, const int* in_sizes, int n_in,
                              void* d_out, int out_size, void* d_ws, size_t ws_size,
                              hipStream_t stream) {
    const float* cf      = (const float*)d_in[0];
    const float* vf      = (const float*)d_in[1];
    const int*   c2v_src = (const int*)d_in[2];
    const int*   c2v_tgt = (const int*)d_in[3];
    const int*   v2c_src = (const int*)d_in[4];
    const int*   v2c_tgt = (const int*)d_in[5];
    const float* Wc_in   = (const float*)d_in[6];
    const float* bc_in   = (const float*)d_in[7];
    const float* Wv_in   = (const float*)d_in[8];
    const float* bv_in   = (const float*)d_in[9];
    const float* gc_ln   = (const float*)d_in[10];
    const float* bc_ln   = (const float*)d_in[11];
    const float* gv_ln   = (const float*)d_in[12];
    const float* bv_ln   = (const float*)d_in[13];
    const float* Wmsg_c  = (const float*)d_in[14];
    const float* bmsg_c  = (const float*)d_in[15];
    const float* Wmsg_v  = (const float*)d_in[16];
    const float* bmsg_v  = (const float*)d_in[17];
    const float* Wns_c   = (const float*)d_in[18];
    const float* bns_c   = (const float*)d_in[19];
    const float* Wns_v   = (const float*)d_in[20];
    const float* bns_v   = (const float*)d_in[21];
    const float* Wg_c    = (const float*)d_in[22];
    const float* Ug_c    = (const float*)d_in[23];
    const float* bg_c    = (const float*)d_in[24];
    const float* Wg_v    = (const float*)d_in[25];
    const float* Ug_v    = (const float*)d_in[26];
    const float* bg_v    = (const float*)d_in[27];
    const float* Wf      = (const float*)d_in[28];
    const float* bf      = (const float*)d_in[29];
    float* out = (float*)d_out;

    // ---- workspace carve (256B-aligned) ----
    char* p = (char*)d_ws;
    #define CARVE(name, type, count) type* name = (type*)p; p += (((size_t)(count) * sizeof(type)) + 255) & ~(size_t)255;
    CARVE(hc,     float, NCn * Hdim)
    CARVE(hv,     float, NVn * Hdim)
    CARVE(hc_b,   unsigned short, NCn * Hdim)
    CARVE(hv_b,   unsigned short, NVn * Hdim)
    CARVE(Pv0,    unsigned short, NVn * Hdim)
    CARVE(Qc0,    unsigned short, NCn * Hdim)
    CARVE(Pc0,    unsigned short, NCn * Hdim)
    CARVE(Qv0,    unsigned short, NVn * Hdim)
    CARVE(Pv1,    unsigned short, NVn * Hdim)
    CARVE(Qc1,    unsigned short, NCn * Hdim)
    CARVE(Pc1,    unsigned short, NCn * Hdim)
    CARVE(Qv1,    unsigned short, NVn * Hdim)
    CARVE(Fmsg_c, unsigned short, 32768)
    CARVE(Fmsg_v, unsigned short, 32768)
    CARVE(Fns_c,  unsigned short, 32768)
    CARVE(Fns_v,  unsigned short, 32768)
    CARVE(Fcat_c, unsigned short, 98304)
    CARVE(Fuh_c,  unsigned short, 16384)
    CARVE(Fcat_v, unsigned short, 98304)
    CARVE(Fuh_v,  unsigned short, 16384)
    CARVE(rp_c,  int, NCn + 8)
    CARVE(rp_v,  int, NVn + 8)
    CARVE(srcs_c, int, NE)
    CARVE(srcs_v, int, NE)
    CARVE(cnts,  int, 48000)
    #undef CARVE
    int* cnt_c  = cnts;
    int* cnt_v  = cnts + NCn;
    int* fill_c = cnts + NCn + NVn;
    int* fill_v = cnts + 2 * NCn + NVn;

    // ---- once-per-call prep ----
    prep_weights<<<(4 * 32768 + 2 * 98304 + 2 * 16384 + 255) / 256, 256, 0, stream>>>(
        Wmsg_c, Wmsg_v, Wns_c, Wns_v, Wg_c, Ug_c, Wg_v, Ug_v,
        Fmsg_c, Fmsg_v, Fns_c, Fns_v, Fcat_c, Fuh_c, Fcat_v, Fuh_v);
    zero_int_kernel<<<(48000 + 255) / 256, 256, 0, stream>>>(cnts, 48000);
    hist_kernel<<<(NE + 255) / 256, 256, 0, stream>>>(v2c_tgt, c2v_tgt, cnt_c, cnt_v);
    scan_kernel<<<1, 1024, 0, stream>>>(cnt_c, rp_c, NCn);
    scan_kernel<<<1, 1024, 0, stream>>>(cnt_v, rp_v, NVn);
    fill_kernel<<<(NE + 255) / 256, 256, 0, stream>>>(v2c_tgt, c2v_tgt, v2c_src, c2v_src,
                                                      rp_c, rp_v, fill_c, fill_v, srcs_c, srcs_v);
    init_kernel<<<NCn + NVn, 64, 0, stream>>>(cf, vf, Wc_in, bc_in, Wv_in, bv_in,
                                              gc_ln, bc_ln, gv_ln, bv_ln, hc, hv, hc_b, hv_b);
    pq_init<<<NCB32 + NVB32, 256, 0, stream>>>(hc_b, hv_b, Fmsg_c, Fmsg_v, bmsg_c, bmsg_v,
                                               Pv0, Qc0, Pc0, Qv0);

    unsigned short* Pv_[2] = {Pv0, Pv1};
    unsigned short* Qc_[2] = {Qc0, Qc1};
    unsigned short* Pc_[2] = {Pc0, Pc1};
    unsigned short* Qv_[2] = {Qv0, Qv1};

    for (int it = 0; it < LITERS; it++) {
        int rd = it & 1, wr = rd ^ 1;
        node_fused<<<NCB16 + NVB16, 256, 0, stream>>>(
            hc, hv, hc_b, hv_b, rp_c, rp_v, srcs_c, srcs_v,
            Pv_[rd], Qc_[rd], Pc_[rd], Qv_[rd],
            Pv_[wr], Qc_[wr], Pc_[wr], Qv_[wr],
            Fns_c, bns_c, Fns_v, bns_v,
            Fcat_c, Fuh_c, Fcat_v, Fuh_v, bg_c, bg_v,
            Fmsg_c, Fmsg_v, bmsg_c, bmsg_v,
            (it < LITERS - 1) ? 1 : 0);
    }

    final_kernel<<<NVn / 4, 256, 0, stream>>>(hv, Wf, bf, out);
}